// Round 4
// baseline (262.136 us; speedup 1.0000x reference)
//
#include <hip/hip_runtime.h>

#define N_NODES 50000
#define N_EDGES 800000
#define IN_DIM 64
#define HID_DIM 128
#define OUT_DIM 10
#define N_GRAPHS 64

#define NBUCK ((N_NODES + 255) / 256)         // 196 coarse buckets of 256 nodes

typedef short bf16x8 __attribute__((ext_vector_type(8)));
typedef float f32x4  __attribute__((ext_vector_type(4)));

// ---- bf16 pack/unpack helpers (RNE pack; unpack = shift/mask) ----
__device__ __forceinline__ unsigned bf16pack2(float a, float b) {
    unsigned ua = __float_as_uint(a), ub = __float_as_uint(b);
    ua = (ua + 0x7FFFu + ((ua >> 16) & 1u)) >> 16;
    ub = (ub + 0x7FFFu + ((ub >> 16) & 1u)) >> 16;
    return ua | (ub << 16);
}
__device__ __forceinline__ unsigned short bf16r(float v) {
    unsigned u = __float_as_uint(v);
    u = (u + 0x7FFFu + ((u >> 16) & 1u)) >> 16;
    return (unsigned short)u;
}
__device__ __forceinline__ float bf16lo(unsigned u) { return __uint_as_float(u << 16); }
__device__ __forceinline__ float bf16hi(unsigned u) { return __uint_as_float(u & 0xFFFF0000u); }

// ---------------- hist: per-block coarse histogram (no global atomics) ----------------
// + fused: graph bounds from sorted batch; weight fp32->bf16 pack; psum/fc_cnt zero (block 0)

__global__ __launch_bounds__(256) void k_hist(const int* __restrict__ dst,
                                              const int* __restrict__ batch,
                                              const float* __restrict__ w1,
                                              const float* __restrict__ w2,
                                              int* __restrict__ hpart,
                                              int* __restrict__ gstart,
                                              unsigned* __restrict__ w1b,
                                              unsigned* __restrict__ w2b,
                                              float* __restrict__ psum,
                                              int* __restrict__ fc_cnt) {
    __shared__ int cnt[NBUCK];
    const int tid = threadIdx.x;
    const int b = blockIdx.x;          // 196 blocks
    for (int f = tid; f < NBUCK; f += 256) cnt[f] = 0;
    __syncthreads();

    const int base4 = b * 1024 + tid;  // int4 index over dst
#pragma unroll
    for (int r = 0; r < 4; r++) {
        int i4 = base4 + r * 256;
        if (i4 < N_EDGES / 4) {
            int4 d4 = ((const int4*)dst)[i4];
            atomicAdd(&cnt[d4.x >> 8], 1);
            atomicAdd(&cnt[d4.y >> 8], 1);
            atomicAdd(&cnt[d4.z >> 8], 1);
            atomicAdd(&cnt[d4.w >> 8], 1);
        }
    }
    __syncthreads();
    for (int f = tid; f < NBUCK; f += 256) hpart[b * NBUCK + f] = cnt[f];

    // fused: graph boundaries (batch sorted)
    int node = b * 256 + tid;
    if (node < N_NODES) {
        int bb = batch[node];
        if (node == 0) {
            for (int g = 0; g <= bb; g++) gstart[g] = 0;
        } else {
            int a = batch[node - 1];
            for (int g = a + 1; g <= bb; g++) gstart[g] = node;
        }
        if (node == N_NODES - 1) {
            for (int g = bb + 1; g <= N_GRAPHS; g++) gstart[g] = N_NODES;
        }
    }

    // fused: weight pack (12288 float2 -> uint)
    int i = b * 256 + tid;
    if (i < 4096) {
        float2 v = ((const float2*)w1)[i];
        w1b[i] = bf16pack2(v.x, v.y);
    } else if (i < 12288) {
        int j = i - 4096;
        float2 v = ((const float2*)w2)[j];
        w2b[j] = bf16pack2(v.x, v.y);
    }

    // fused: zero pooled-sum accumulator + last-block counter (block 0; long before gemm2)
    if (b == 0) {
        for (int p = tid; p < N_GRAPHS * HID_DIM; p += 256) psum[p] = 0.f;
        if (tid == 0) fc_cnt[0] = 0;
    }
}

// ---------------- fill1b: per-block self-scan of hpart -> deterministic placement ----------------

__global__ __launch_bounds__(256) void k_fill1b(const int* __restrict__ src,
                                                const int* __restrict__ dst,
                                                const int* __restrict__ hpart,
                                                int* __restrict__ gbase,
                                                unsigned* __restrict__ ebuf) {
    __shared__ int s[256];
    __shared__ int base[NBUCK], hrun[NBUCK];
    const int tid = threadIdx.x;
    const int b = blockIdx.x;          // 196 blocks

    // column totals + this-block exclusive prefix (rows b' < b)
    int tot = 0, mine = 0;
    if (tid < NBUCK) {
        for (int bb = 0; bb < NBUCK; bb++) {
            int v = hpart[bb * NBUCK + tid];   // coalesced across tid
            tot += v;
            if (bb < b) mine += v;
        }
    }
    s[tid] = (tid < NBUCK) ? tot : 0;
    for (int f = tid; f < NBUCK; f += 256) hrun[f] = 0;
    __syncthreads();
#pragma unroll
    for (int off = 1; off < 256; off <<= 1) {
        int v = (tid >= off) ? s[tid - off] : 0;
        __syncthreads();
        s[tid] += v;
        __syncthreads();
    }
    if (tid < NBUCK) {
        int ex = (tid > 0) ? s[tid - 1] : 0;
        base[tid] = ex + mine;
        if (b == 0) gbase[tid] = ex;          // publish bucket bounds for fill2
    }
    if (b == 0 && tid == 0) gbase[NBUCK] = N_EDGES;
    __syncthreads();

    // scatter this block's edges into their reserved slots
    const int base4 = b * 1024 + tid;
#pragma unroll
    for (int r = 0; r < 4; r++) {
        int i4 = base4 + r * 256;
        if (i4 < N_EDGES / 4) {
            int4 s4 = ((const int4*)src)[i4];
            int4 d4 = ((const int4*)dst)[i4];
            int dd[4] = {d4.x, d4.y, d4.z, d4.w};
            int ss[4] = {s4.x, s4.y, s4.z, s4.w};
#pragma unroll
            for (int k = 0; k < 4; k++) {
                int bk = dd[k] >> 8;
                int pos = base[bk] + atomicAdd(&hrun[bk], 1);
                ebuf[pos] = (unsigned)ss[k] | ((unsigned)(dd[k] & 255) << 16);
            }
        }
    }
}

// ---------------- fill2: per-bucket fine sort + row_ptr + dinv + col + xs ----------------

__global__ __launch_bounds__(256) void k_fill2(const unsigned* __restrict__ ebuf,
                                               const int* __restrict__ gbase,
                                               const float* __restrict__ x,
                                               int* __restrict__ row_ptr,
                                               float* __restrict__ dinv,
                                               unsigned short* __restrict__ col,
                                               unsigned* __restrict__ xs) {
    __shared__ int cnt[256], cur[256], s[256];
    __shared__ float dv[256];
    const int b = blockIdx.x;       // 196 blocks
    const int f = threadIdx.x;
    const int start = gbase[b], endr = gbase[b + 1];

    cnt[f] = 0;
    __syncthreads();
    for (int i = start + f; i < endr; i += 256)
        atomicAdd(&cnt[(ebuf[i] >> 16) & 0xFF], 1);
    __syncthreads();

    int d = cnt[f];
    s[f] = d;
    __syncthreads();
#pragma unroll
    for (int off = 1; off < 256; off <<= 1) {
        int v = (f >= off) ? s[f - off] : 0;
        __syncthreads();
        s[f] += v;
        __syncthreads();
    }
    int excl = start + s[f] - d;
    int node = b * 256 + f;
    if (node < N_NODES) {
        row_ptr[node] = excl;
        float dvv = rsqrtf((float)(d + 1));
        dinv[node] = dvv;
        dv[f] = dvv;
    }
    cur[f] = excl;
    if (b == 0 && f == 0) row_ptr[N_NODES] = N_EDGES;
    __syncthreads();

    for (int i = start + f; i < endr; i += 256) {
        unsigned e = ebuf[i];
        int pos = atomicAdd(&cur[(e >> 16) & 0xFF], 1);
        col[pos] = (unsigned short)(e & 0xFFFFu);
    }

    // fused xscale for this bucket's nodes
    const int lo = b * 256;
    for (int j = f; j < 256 * 32; j += 256) {
        int nl = j >> 5;
        int m = lo + nl;
        if (m < N_NODES) {
            int chunk = j & 31;
            float2 v = ((const float2*)x)[(size_t)m * 32 + chunk];
            float dm = dv[nl];
            xs[(size_t)m * 32 + chunk] = bf16pack2(dm * v.x, dm * v.y);
        }
    }
}

// ---------------- gather64 (wide): 8 lanes/row, 16B loads; agg[d] = bf16(dinv*(xs[d]+sum xs[s])) ----------------

__global__ __launch_bounds__(256) void k_gather64(const unsigned* __restrict__ xs,
                                                  const int* __restrict__ row_ptr,
                                                  const unsigned short* __restrict__ col,
                                                  const float* __restrict__ dinv,
                                                  unsigned* __restrict__ agg) {
    const int g = blockIdx.x * 32 + (threadIdx.x >> 3);   // 32 rows/block, grid 1563
    if (g >= N_NODES) return;
    const int l = threadIdx.x & 7;                        // 16B lane: dims 8l..8l+7
    const uint4* xsv = (const uint4*)xs;                  // row = 8 uint4 (128B)

    uint4 v = xsv[(size_t)g * 8 + l];
    float a0 = bf16lo(v.x), a1 = bf16hi(v.x), a2 = bf16lo(v.y), a3 = bf16hi(v.y);
    float a4 = bf16lo(v.z), a5 = bf16hi(v.z), a6 = bf16lo(v.w), a7 = bf16hi(v.w);

    const int beg = row_ptr[g], end = row_ptr[g + 1];
    for (int j = beg; j < end; j += 8) {
        int idx[8]; float wt[8];
#pragma unroll
        for (int k = 0; k < 8; k++) {
            int jj = j + k;
            bool in = jj < end;
            idx[k] = in ? jj : (end - 1);
            wt[k] = in ? 1.f : 0.f;
        }
        int s[8];
#pragma unroll
        for (int k = 0; k < 8; k++) s[k] = col[idx[k]];
        uint4 u[8];
#pragma unroll
        for (int k = 0; k < 8; k++) u[k] = xsv[(size_t)s[k] * 8 + l];
#pragma unroll
        for (int k = 0; k < 8; k++) {
            a0 = fmaf(wt[k], bf16lo(u[k].x), a0); a1 = fmaf(wt[k], bf16hi(u[k].x), a1);
            a2 = fmaf(wt[k], bf16lo(u[k].y), a2); a3 = fmaf(wt[k], bf16hi(u[k].y), a3);
            a4 = fmaf(wt[k], bf16lo(u[k].z), a4); a5 = fmaf(wt[k], bf16hi(u[k].z), a5);
            a6 = fmaf(wt[k], bf16lo(u[k].w), a6); a7 = fmaf(wt[k], bf16hi(u[k].w), a7);
        }
    }
    float dm = dinv[g];
    uint4 o;
    o.x = bf16pack2(dm * a0, dm * a1);
    o.y = bf16pack2(dm * a2, dm * a3);
    o.z = bf16pack2(dm * a4, dm * a5);
    o.w = bf16pack2(dm * a6, dm * a7);
    ((uint4*)agg)[(size_t)g * 8 + l] = o;
}

// ---------------- gather128b (wide): 16 lanes/row, 16B loads; out[d] = bf16(dinv*(ts[d]+sum ts[s])) ----------------

__global__ __launch_bounds__(256) void k_gather128b(const unsigned* __restrict__ ts,
                                                    const int* __restrict__ row_ptr,
                                                    const unsigned short* __restrict__ col,
                                                    const float* __restrict__ dinv,
                                                    unsigned* __restrict__ outb) {
    const int g = blockIdx.x * 16 + (threadIdx.x >> 4);   // 16 rows/block, grid 3125 exact
    const int l = threadIdx.x & 15;                       // 16B lane: dims 8l..8l+7
    const uint4* tsv = (const uint4*)ts;                  // row = 16 uint4 (256B)

    uint4 v = tsv[(size_t)g * 16 + l];
    float a0 = bf16lo(v.x), a1 = bf16hi(v.x), a2 = bf16lo(v.y), a3 = bf16hi(v.y);
    float a4 = bf16lo(v.z), a5 = bf16hi(v.z), a6 = bf16lo(v.w), a7 = bf16hi(v.w);

    const int beg = row_ptr[g], end = row_ptr[g + 1];
    for (int j = beg; j < end; j += 8) {
        int idx[8]; float wt[8];
#pragma unroll
        for (int k = 0; k < 8; k++) {
            int jj = j + k;
            bool in = jj < end;
            idx[k] = in ? jj : (end - 1);
            wt[k] = in ? 1.f : 0.f;
        }
        int s[8];
#pragma unroll
        for (int k = 0; k < 8; k++) s[k] = col[idx[k]];
        uint4 u[8];
#pragma unroll
        for (int k = 0; k < 8; k++) u[k] = tsv[(size_t)s[k] * 16 + l];
#pragma unroll
        for (int k = 0; k < 8; k++) {
            a0 = fmaf(wt[k], bf16lo(u[k].x), a0); a1 = fmaf(wt[k], bf16hi(u[k].x), a1);
            a2 = fmaf(wt[k], bf16lo(u[k].y), a2); a3 = fmaf(wt[k], bf16hi(u[k].y), a3);
            a4 = fmaf(wt[k], bf16lo(u[k].z), a4); a5 = fmaf(wt[k], bf16hi(u[k].z), a5);
            a6 = fmaf(wt[k], bf16lo(u[k].w), a6); a7 = fmaf(wt[k], bf16hi(u[k].w), a7);
        }
    }
    float dm = dinv[g];
    uint4 o;
    o.x = bf16pack2(dm * a0, dm * a1);
    o.y = bf16pack2(dm * a2, dm * a3);
    o.z = bf16pack2(dm * a4, dm * a5);
    o.w = bf16pack2(dm * a6, dm * a7);
    ((uint4*)outb)[(size_t)g * 16 + l] = o;
}

// ---------------- MFMA bf16 GEMM: D[m][n] = sum_k X[m][k]*W[n][k]  (N=128) ----------------
// MODE 1: Ob = bf16(dinv[m] * relu(acc + bias[n]))      (layer-1 out, pre-scaled for aggregation)
// MODE 2: h = relu(acc + bias[n]); fused mean-pool -> atomicAdd psum; last block runs FC head.

template<int K, int MODE>
__global__ __launch_bounds__(256) void k_gemm_mfma(const unsigned* __restrict__ Xb,
                                                   const unsigned* __restrict__ Wb,
                                                   const float* __restrict__ bias,
                                                   const float* __restrict__ dinv,
                                                   const int* __restrict__ batch,
                                                   float* __restrict__ psum,
                                                   unsigned short* __restrict__ Ob,
                                                   const int* __restrict__ gstart,
                                                   const float* __restrict__ fcw,
                                                   const float* __restrict__ fcb,
                                                   float* __restrict__ out,
                                                   int* __restrict__ fc_cnt) {
    constexpr int KU  = K / 2;
    constexpr int SP  = K + 8;
    constexpr int SPU = SP / 2;
    __shared__ __align__(16) unsigned smem[64 * SPU + 128 * SPU];
    __shared__ int sbat[64];
    __shared__ int winner;
    unsigned* As_u = smem;
    unsigned* Bs_u = smem + 64 * SPU;

    const int tid = threadIdx.x;
    const int bm = blockIdx.x * 64;

    for (int i = tid; i < 64 * KU; i += 256) {
        int r = i / KU, c = i % KU;
        int m = bm + r;
        As_u[r * SPU + c] = (m < N_NODES) ? Xb[(size_t)m * KU + c] : 0u;
    }
    for (int i = tid; i < 128 * KU; i += 256) {
        int r = i / KU, c = i % KU;
        Bs_u[r * SPU + c] = Wb[r * KU + c];
    }
    if constexpr (MODE == 2) {
        if (tid < 64) sbat[tid] = (bm + tid < N_NODES) ? batch[bm + tid] : -1;
    }
    __syncthreads();

    const int wv = tid >> 6;
    const int lane = tid & 63;
    const int lr = lane & 15;
    const int q = lane >> 4;

    f32x4 acc[8];
#pragma unroll
    for (int nt = 0; nt < 8; nt++) acc[nt] = (f32x4){0.f, 0.f, 0.f, 0.f};

    const short* As_s = (const short*)As_u;
    const short* Bs_s = (const short*)Bs_u;
#pragma unroll
    for (int k0 = 0; k0 < K; k0 += 32) {
        bf16x8 a = *(const bf16x8*)(As_s + (wv * 16 + lr) * SP + k0 + q * 8);
#pragma unroll
        for (int nt = 0; nt < 8; nt++) {
            bf16x8 b = *(const bf16x8*)(Bs_s + (nt * 16 + lr) * SP + k0 + q * 8);
            acc[nt] = __builtin_amdgcn_mfma_f32_16x16x32_bf16(a, b, acc[nt], 0, 0, 0);
        }
    }

    if constexpr (MODE == 1) {
        float dv_[4];
#pragma unroll
        for (int i = 0; i < 4; i++) {
            int m = bm + wv * 16 + q * 4 + i;
            dv_[i] = (m < N_NODES) ? dinv[m] : 0.f;
        }
#pragma unroll
        for (int nt = 0; nt < 8; nt++) {
            int cN = nt * 16 + lr;
            float bv = bias[cN];
#pragma unroll
            for (int i = 0; i < 4; i++) {
                int m = bm + wv * 16 + q * 4 + i;
                if (m < N_NODES)
                    Ob[(size_t)m * HID_DIM + cN] = bf16r(dv_[i] * fmaxf(acc[nt][i] + bv, 0.f));
            }
        }
    } else {
        // fused mean-pool: write relu'd h-tile into (dead) LDS, run-reduce per column
        __syncthreads();                       // all MFMA LDS reads complete before overwrite
        float* hl = (float*)smem;              // [64][132] fp32 tile (33.8 KB < 52.2 KB)
#pragma unroll
        for (int nt = 0; nt < 8; nt++) {
            int cN = nt * 16 + lr;
            float bv = bias[cN];
#pragma unroll
            for (int i = 0; i < 4; i++) {
                int mr = wv * 16 + q * 4 + i;
                if (bm + mr < N_NODES)
                    hl[mr * 132 + cN] = fmaxf(acc[nt][i] + bv, 0.f);
            }
        }
        __syncthreads();
        if (tid < 128) {
            int f = tid;
            float run = 0.f;
            int cg = sbat[0];
            for (int m = 0; m < 64; m++) {
                int g = sbat[m];
                if (g != cg) {
                    if (cg >= 0) atomicAdd(&psum[cg * HID_DIM + f], run);
                    run = 0.f;
                    cg = g;
                }
                if (g >= 0) run += hl[m * 132 + f];
            }
            if (cg >= 0) atomicAdd(&psum[cg * HID_DIM + f], run);
        }

        // ---- last-block FC head (saves a dependent dispatch) ----
        __threadfence();
        __syncthreads();                       // barrier waits each thread's vmcnt -> psum atomics complete
        if (tid == 0)
            winner = (atomicAdd(fc_cnt, 1) == (int)gridDim.x - 1) ? 1 : 0;
        __syncthreads();
        if (winner) {
            float* pl = (float*)smem;          // 8192 floats = 32 KB (smem is dead again)
            for (int i = tid; i < N_GRAPHS * HID_DIM; i += 256) {
                int g = i >> 7;
                float c = fmaxf((float)(gstart[g + 1] - gstart[g]), 1.f);
                pl[i] = atomicAdd(&psum[i], 0.f) / c;   // coherent-point read
            }
            __syncthreads();
            for (int wk = tid; wk < N_GRAPHS * OUT_DIM; wk += 256) {
                int g = wk / OUT_DIM, o = wk - g * OUT_DIM;
                float a = fcb[o];
#pragma unroll 8
                for (int k = 0; k < HID_DIM; k++)
                    a = fmaf(pl[g * HID_DIM + k], fcw[o * HID_DIM + k], a);
                out[g * OUT_DIM + o] = a;
            }
        }
    }
}

// ---------------- launch ----------------

extern "C" void kernel_launch(void* const* d_in, const int* in_sizes, int n_in,
                              void* d_out, int out_size, void* d_ws, size_t ws_size,
                              hipStream_t stream) {
    const float* x   = (const float*)d_in[0];
    const int*  eidx = (const int*)d_in[1];
    const int* batch = (const int*)d_in[2];
    const float* w1  = (const float*)d_in[3];
    const float* b1  = (const float*)d_in[4];
    const float* w2  = (const float*)d_in[5];
    const float* b2  = (const float*)d_in[6];
    const float* fcw = (const float*)d_in[7];
    const float* fcb = (const float*)d_in[8];
    float* out = (float*)d_out;
    const int* src = eidx;             // edge_index[0]
    const int* dst = eidx + N_EDGES;   // edge_index[1]

    char* w = (char*)d_ws;
    unsigned* xs   = (unsigned*)(w);                  //  6,400,000 B  x * dinv (bf16)
    unsigned* aggb = (unsigned*)(w + 6400000);        //  6,400,000 B  layer-1 aggregate (bf16)
    unsigned short* h1s = (unsigned short*)(w + 12800000);  // 12,800,000 B  dinv*relu(h1) (bf16)
    unsigned* agg2 = (unsigned*)(w + 25600000);       // 12,800,000 B  layer-2 aggregate (bf16)
    unsigned* ebuf = (unsigned*)(w + 38400000);       //  3,200,000 B  CSR build scratch
    int*   row_ptr = (int*)  (w + 51200000);          //    200,064 B
    float* dinv    = (float*)(w + 51400064);          //    200,000 B
    unsigned short* col = (unsigned short*)(w + 51600064);  // 1,600,000 B (u16)
    int*   hpart   = (int*)  (w + 53200064);          //    153,664 B (196*196)
    int*   gbase   = (int*)  (w + 53353728);          //        788 B (197 ints)
    int*   gstart  = (int*)  (w + 53354516);          //        260 B
    unsigned* w1b  = (unsigned*)(w + 53355584);       //     16,384 B
    unsigned* w2b  = (unsigned*)(w + 53371968);       //     32,768 B
    float* psum    = (float*)(w + 53404736);          //     32,768 B (64*128 fp32 pooled sums)
    int*   fc_cnt  = (int*)  (w + 53437504);          //          4 B (last-block counter)

    dim3 b256(256);

    // CSR build: hist (+bounds/wpack/psum0) -> self-scan scatter -> fine sort (+xscale)
    k_hist  <<<dim3(NBUCK), b256, 0, stream>>>(dst, batch, w1, w2, hpart, gstart, w1b, w2b, psum, fc_cnt);
    k_fill1b<<<dim3(NBUCK), b256, 0, stream>>>(src, dst, hpart, gbase, ebuf);
    k_fill2 <<<dim3(NBUCK), b256, 0, stream>>>(ebuf, gbase, x, row_ptr, dinv, col, xs);

    // layer 1 (aggregate-then-transform, all-bf16 payloads); epilogue pre-scales by dinv
    k_gather64<<<dim3((N_NODES + 31) / 32), b256, 0, stream>>>(xs, row_ptr, col, dinv, aggb);
    k_gemm_mfma<IN_DIM, 1><<<dim3((N_NODES + 63) / 64), b256, 0, stream>>>(
        aggb, w1b, b1, dinv, nullptr, nullptr, h1s, nullptr, nullptr, nullptr, nullptr, nullptr);

    // layer 2 (aggregate-then-transform; GEMM epilogue fuses relu + mean-pool + last-block FC)
    k_gather128b<<<dim3(N_NODES / 16), b256, 0, stream>>>(h1s == nullptr ? nullptr : (const unsigned*)h1s,
                                                          row_ptr, col, dinv, agg2);
    k_gemm_mfma<HID_DIM, 2><<<dim3((N_NODES + 63) / 64), b256, 0, stream>>>(
        (const unsigned*)agg2, w2b, b2, nullptr, batch, psum, nullptr, gstart, fcw, fcb, out, fc_cnt);
}

// Round 5
// 200.584 us; speedup vs baseline: 1.3069x; 1.3069x over previous
//
#include <hip/hip_runtime.h>

#define N_NODES 50000
#define N_EDGES 800000
#define IN_DIM 64
#define HID_DIM 128
#define OUT_DIM 10
#define N_GRAPHS 64

#define NBUCK ((N_NODES + 255) / 256)         // 196 coarse buckets of 256 nodes

typedef short bf16x8 __attribute__((ext_vector_type(8)));
typedef float f32x4  __attribute__((ext_vector_type(4)));

// ---- bf16 pack/unpack helpers (RNE pack; unpack = shift/mask) ----
__device__ __forceinline__ unsigned bf16pack2(float a, float b) {
    unsigned ua = __float_as_uint(a), ub = __float_as_uint(b);
    ua = (ua + 0x7FFFu + ((ua >> 16) & 1u)) >> 16;
    ub = (ub + 0x7FFFu + ((ub >> 16) & 1u)) >> 16;
    return ua | (ub << 16);
}
__device__ __forceinline__ unsigned short bf16r(float v) {
    unsigned u = __float_as_uint(v);
    u = (u + 0x7FFFu + ((u >> 16) & 1u)) >> 16;
    return (unsigned short)u;
}
__device__ __forceinline__ float bf16lo(unsigned u) { return __uint_as_float(u << 16); }
__device__ __forceinline__ float bf16hi(unsigned u) { return __uint_as_float(u & 0xFFFF0000u); }

// ---------------- hist: per-block coarse histogram (no global atomics) ----------------
// + fused: graph bounds from sorted batch; weight fp32->bf16 pack; psum zero (block 0)

__global__ __launch_bounds__(256) void k_hist(const int* __restrict__ dst,
                                              const int* __restrict__ batch,
                                              const float* __restrict__ w1,
                                              const float* __restrict__ w2,
                                              int* __restrict__ hpart,
                                              int* __restrict__ gstart,
                                              unsigned* __restrict__ w1b,
                                              unsigned* __restrict__ w2b,
                                              float* __restrict__ psum) {
    __shared__ int cnt[NBUCK];
    const int tid = threadIdx.x;
    const int b = blockIdx.x;          // 196 blocks
    for (int f = tid; f < NBUCK; f += 256) cnt[f] = 0;
    __syncthreads();

    const int base4 = b * 1024 + tid;  // int4 index over dst
#pragma unroll
    for (int r = 0; r < 4; r++) {
        int i4 = base4 + r * 256;
        if (i4 < N_EDGES / 4) {
            int4 d4 = ((const int4*)dst)[i4];
            atomicAdd(&cnt[d4.x >> 8], 1);
            atomicAdd(&cnt[d4.y >> 8], 1);
            atomicAdd(&cnt[d4.z >> 8], 1);
            atomicAdd(&cnt[d4.w >> 8], 1);
        }
    }
    __syncthreads();
    for (int f = tid; f < NBUCK; f += 256) hpart[b * NBUCK + f] = cnt[f];

    // fused: graph boundaries (batch sorted)
    int node = b * 256 + tid;
    if (node < N_NODES) {
        int bb = batch[node];
        if (node == 0) {
            for (int g = 0; g <= bb; g++) gstart[g] = 0;
        } else {
            int a = batch[node - 1];
            for (int g = a + 1; g <= bb; g++) gstart[g] = node;
        }
        if (node == N_NODES - 1) {
            for (int g = bb + 1; g <= N_GRAPHS; g++) gstart[g] = N_NODES;
        }
    }

    // fused: weight pack (12288 float2 -> uint)
    int i = b * 256 + tid;
    if (i < 4096) {
        float2 v = ((const float2*)w1)[i];
        w1b[i] = bf16pack2(v.x, v.y);
    } else if (i < 12288) {
        int j = i - 4096;
        float2 v = ((const float2*)w2)[j];
        w2b[j] = bf16pack2(v.x, v.y);
    }

    // fused: zero the pooled-sum accumulator (block 0; runs long before gemm2)
    if (b == 0)
        for (int p = tid; p < N_GRAPHS * HID_DIM; p += 256) psum[p] = 0.f;
}

// ---------------- fill1b: per-block self-scan of hpart -> deterministic placement ----------------

__global__ __launch_bounds__(256) void k_fill1b(const int* __restrict__ src,
                                                const int* __restrict__ dst,
                                                const int* __restrict__ hpart,
                                                int* __restrict__ gbase,
                                                unsigned* __restrict__ ebuf) {
    __shared__ int s[256];
    __shared__ int base[NBUCK], hrun[NBUCK];
    const int tid = threadIdx.x;
    const int b = blockIdx.x;          // 196 blocks

    // column totals + this-block exclusive prefix (rows b' < b)
    int tot = 0, mine = 0;
    if (tid < NBUCK) {
        for (int bb = 0; bb < NBUCK; bb++) {
            int v = hpart[bb * NBUCK + tid];   // coalesced across tid
            tot += v;
            if (bb < b) mine += v;
        }
    }
    s[tid] = (tid < NBUCK) ? tot : 0;
    for (int f = tid; f < NBUCK; f += 256) hrun[f] = 0;
    __syncthreads();
#pragma unroll
    for (int off = 1; off < 256; off <<= 1) {
        int v = (tid >= off) ? s[tid - off] : 0;
        __syncthreads();
        s[tid] += v;
        __syncthreads();
    }
    if (tid < NBUCK) {
        int ex = (tid > 0) ? s[tid - 1] : 0;
        base[tid] = ex + mine;
        if (b == 0) gbase[tid] = ex;          // publish bucket bounds for fill2
    }
    if (b == 0 && tid == 0) gbase[NBUCK] = N_EDGES;
    __syncthreads();

    // scatter this block's edges into their reserved slots
    const int base4 = b * 1024 + tid;
#pragma unroll
    for (int r = 0; r < 4; r++) {
        int i4 = base4 + r * 256;
        if (i4 < N_EDGES / 4) {
            int4 s4 = ((const int4*)src)[i4];
            int4 d4 = ((const int4*)dst)[i4];
            int dd[4] = {d4.x, d4.y, d4.z, d4.w};
            int ss[4] = {s4.x, s4.y, s4.z, s4.w};
#pragma unroll
            for (int k = 0; k < 4; k++) {
                int bk = dd[k] >> 8;
                int pos = base[bk] + atomicAdd(&hrun[bk], 1);
                ebuf[pos] = (unsigned)ss[k] | ((unsigned)(dd[k] & 255) << 16);
            }
        }
    }
}

// ---------------- fill2: per-bucket fine sort + row_ptr + dinv + col + xs ----------------

__global__ __launch_bounds__(256) void k_fill2(const unsigned* __restrict__ ebuf,
                                               const int* __restrict__ gbase,
                                               const float* __restrict__ x,
                                               int* __restrict__ row_ptr,
                                               float* __restrict__ dinv,
                                               unsigned short* __restrict__ col,
                                               unsigned* __restrict__ xs) {
    __shared__ int cnt[256], cur[256], s[256];
    __shared__ float dv[256];
    const int b = blockIdx.x;       // 196 blocks
    const int f = threadIdx.x;
    const int start = gbase[b], endr = gbase[b + 1];

    cnt[f] = 0;
    __syncthreads();
    for (int i = start + f; i < endr; i += 256)
        atomicAdd(&cnt[(ebuf[i] >> 16) & 0xFF], 1);
    __syncthreads();

    int d = cnt[f];
    s[f] = d;
    __syncthreads();
#pragma unroll
    for (int off = 1; off < 256; off <<= 1) {
        int v = (f >= off) ? s[f - off] : 0;
        __syncthreads();
        s[f] += v;
        __syncthreads();
    }
    int excl = start + s[f] - d;
    int node = b * 256 + f;
    if (node < N_NODES) {
        row_ptr[node] = excl;
        float dvv = rsqrtf((float)(d + 1));
        dinv[node] = dvv;
        dv[f] = dvv;
    }
    cur[f] = excl;
    if (b == 0 && f == 0) row_ptr[N_NODES] = N_EDGES;
    __syncthreads();

    for (int i = start + f; i < endr; i += 256) {
        unsigned e = ebuf[i];
        int pos = atomicAdd(&cur[(e >> 16) & 0xFF], 1);
        col[pos] = (unsigned short)(e & 0xFFFFu);
    }

    // fused xscale for this bucket's nodes
    const int lo = b * 256;
    for (int j = f; j < 256 * 32; j += 256) {
        int nl = j >> 5;
        int m = lo + nl;
        if (m < N_NODES) {
            int chunk = j & 31;
            float2 v = ((const float2*)x)[(size_t)m * 32 + chunk];
            float dm = dv[nl];
            xs[(size_t)m * 32 + chunk] = bf16pack2(dm * v.x, dm * v.y);
        }
    }
}

// ---------------- gather64 (wide): 8 lanes/row, 16B loads; agg[d] = bf16(dinv*(xs[d]+sum xs[s])) ----------------

__global__ __launch_bounds__(256) void k_gather64(const unsigned* __restrict__ xs,
                                                  const int* __restrict__ row_ptr,
                                                  const unsigned short* __restrict__ col,
                                                  const float* __restrict__ dinv,
                                                  unsigned* __restrict__ agg) {
    const int g = blockIdx.x * 32 + (threadIdx.x >> 3);   // 32 rows/block, grid 1563
    if (g >= N_NODES) return;
    const int l = threadIdx.x & 7;                        // 16B lane: dims 8l..8l+7
    const uint4* xsv = (const uint4*)xs;                  // row = 8 uint4 (128B)

    uint4 v = xsv[(size_t)g * 8 + l];
    float a0 = bf16lo(v.x), a1 = bf16hi(v.x), a2 = bf16lo(v.y), a3 = bf16hi(v.y);
    float a4 = bf16lo(v.z), a5 = bf16hi(v.z), a6 = bf16lo(v.w), a7 = bf16hi(v.w);

    const int beg = row_ptr[g], end = row_ptr[g + 1];
    for (int j = beg; j < end; j += 8) {
        int idx[8]; float wt[8];
#pragma unroll
        for (int k = 0; k < 8; k++) {
            int jj = j + k;
            bool in = jj < end;
            idx[k] = in ? jj : (end - 1);
            wt[k] = in ? 1.f : 0.f;
        }
        int s[8];
#pragma unroll
        for (int k = 0; k < 8; k++) s[k] = col[idx[k]];
        uint4 u[8];
#pragma unroll
        for (int k = 0; k < 8; k++) u[k] = xsv[(size_t)s[k] * 8 + l];
#pragma unroll
        for (int k = 0; k < 8; k++) {
            a0 = fmaf(wt[k], bf16lo(u[k].x), a0); a1 = fmaf(wt[k], bf16hi(u[k].x), a1);
            a2 = fmaf(wt[k], bf16lo(u[k].y), a2); a3 = fmaf(wt[k], bf16hi(u[k].y), a3);
            a4 = fmaf(wt[k], bf16lo(u[k].z), a4); a5 = fmaf(wt[k], bf16hi(u[k].z), a5);
            a6 = fmaf(wt[k], bf16lo(u[k].w), a6); a7 = fmaf(wt[k], bf16hi(u[k].w), a7);
        }
    }
    float dm = dinv[g];
    uint4 o;
    o.x = bf16pack2(dm * a0, dm * a1);
    o.y = bf16pack2(dm * a2, dm * a3);
    o.z = bf16pack2(dm * a4, dm * a5);
    o.w = bf16pack2(dm * a6, dm * a7);
    ((uint4*)agg)[(size_t)g * 8 + l] = o;
}

// ---------------- gather128b (wide): 16 lanes/row, 16B loads; out[d] = bf16(dinv*(ts[d]+sum ts[s])) ----------------

__global__ __launch_bounds__(256) void k_gather128b(const unsigned* __restrict__ ts,
                                                    const int* __restrict__ row_ptr,
                                                    const unsigned short* __restrict__ col,
                                                    const float* __restrict__ dinv,
                                                    unsigned* __restrict__ outb) {
    const int g = blockIdx.x * 16 + (threadIdx.x >> 4);   // 16 rows/block, grid 3125 exact
    const int l = threadIdx.x & 15;                       // 16B lane: dims 8l..8l+7
    const uint4* tsv = (const uint4*)ts;                  // row = 16 uint4 (256B)

    uint4 v = tsv[(size_t)g * 16 + l];
    float a0 = bf16lo(v.x), a1 = bf16hi(v.x), a2 = bf16lo(v.y), a3 = bf16hi(v.y);
    float a4 = bf16lo(v.z), a5 = bf16hi(v.z), a6 = bf16lo(v.w), a7 = bf16hi(v.w);

    const int beg = row_ptr[g], end = row_ptr[g + 1];
    for (int j = beg; j < end; j += 8) {
        int idx[8]; float wt[8];
#pragma unroll
        for (int k = 0; k < 8; k++) {
            int jj = j + k;
            bool in = jj < end;
            idx[k] = in ? jj : (end - 1);
            wt[k] = in ? 1.f : 0.f;
        }
        int s[8];
#pragma unroll
        for (int k = 0; k < 8; k++) s[k] = col[idx[k]];
        uint4 u[8];
#pragma unroll
        for (int k = 0; k < 8; k++) u[k] = tsv[(size_t)s[k] * 16 + l];
#pragma unroll
        for (int k = 0; k < 8; k++) {
            a0 = fmaf(wt[k], bf16lo(u[k].x), a0); a1 = fmaf(wt[k], bf16hi(u[k].x), a1);
            a2 = fmaf(wt[k], bf16lo(u[k].y), a2); a3 = fmaf(wt[k], bf16hi(u[k].y), a3);
            a4 = fmaf(wt[k], bf16lo(u[k].z), a4); a5 = fmaf(wt[k], bf16hi(u[k].z), a5);
            a6 = fmaf(wt[k], bf16lo(u[k].w), a6); a7 = fmaf(wt[k], bf16hi(u[k].w), a7);
        }
    }
    float dm = dinv[g];
    uint4 o;
    o.x = bf16pack2(dm * a0, dm * a1);
    o.y = bf16pack2(dm * a2, dm * a3);
    o.z = bf16pack2(dm * a4, dm * a5);
    o.w = bf16pack2(dm * a6, dm * a7);
    ((uint4*)outb)[(size_t)g * 16 + l] = o;
}

// ---------------- MFMA bf16 GEMM: D[m][n] = sum_k X[m][k]*W[n][k]  (N=128) ----------------
// MODE 1: Ob = bf16(dinv[m] * relu(acc + bias[n]))      (layer-1 out, pre-scaled for aggregation)
// MODE 2: h = relu(acc + bias[n]); fused mean-pool: per-block LDS reduce -> atomicAdd psum[g][n]

template<int K, int MODE>
__global__ __launch_bounds__(256) void k_gemm_mfma(const unsigned* __restrict__ Xb,
                                                   const unsigned* __restrict__ Wb,
                                                   const float* __restrict__ bias,
                                                   const float* __restrict__ dinv,
                                                   const int* __restrict__ batch,
                                                   float* __restrict__ psum,
                                                   unsigned short* __restrict__ Ob) {
    constexpr int KU  = K / 2;       // row length in uints
    constexpr int KV  = KU / 4;      // row length in uint4
    constexpr int SP  = K + 8;
    constexpr int SPU = SP / 2;
    __shared__ __align__(16) unsigned smem[64 * SPU + 128 * SPU];
    __shared__ int sbat[64];
    unsigned* As_u = smem;
    unsigned* Bs_u = smem + 64 * SPU;

    const int tid = threadIdx.x;
    const int bm = blockIdx.x * 64;

    // vectorized 16B staging (A then B)
    const uint4* Xv = (const uint4*)Xb;
    const uint4* Wv = (const uint4*)Wb;
    for (int i = tid; i < 64 * KV; i += 256) {
        int r = i / KV, c = i % KV;
        int m = bm + r;
        uint4 v = (m < N_NODES) ? Xv[(size_t)m * KV + c] : make_uint4(0u, 0u, 0u, 0u);
        *(uint4*)&As_u[r * SPU + 4 * c] = v;
    }
    for (int i = tid; i < 128 * KV; i += 256) {
        int r = i / KV, c = i % KV;
        *(uint4*)&Bs_u[r * SPU + 4 * c] = Wv[r * KV + c];
    }
    if constexpr (MODE == 2) {
        if (tid < 64) sbat[tid] = (bm + tid < N_NODES) ? batch[bm + tid] : -1;
    }
    __syncthreads();

    const int wv = tid >> 6;
    const int lane = tid & 63;
    const int lr = lane & 15;
    const int q = lane >> 4;

    f32x4 acc[8];
#pragma unroll
    for (int nt = 0; nt < 8; nt++) acc[nt] = (f32x4){0.f, 0.f, 0.f, 0.f};

    const short* As_s = (const short*)As_u;
    const short* Bs_s = (const short*)Bs_u;
#pragma unroll
    for (int k0 = 0; k0 < K; k0 += 32) {
        bf16x8 a = *(const bf16x8*)(As_s + (wv * 16 + lr) * SP + k0 + q * 8);
#pragma unroll
        for (int nt = 0; nt < 8; nt++) {
            bf16x8 b = *(const bf16x8*)(Bs_s + (nt * 16 + lr) * SP + k0 + q * 8);
            acc[nt] = __builtin_amdgcn_mfma_f32_16x16x32_bf16(a, b, acc[nt], 0, 0, 0);
        }
    }

    if constexpr (MODE == 1) {
        float dv_[4];
#pragma unroll
        for (int i = 0; i < 4; i++) {
            int m = bm + wv * 16 + q * 4 + i;
            dv_[i] = (m < N_NODES) ? dinv[m] : 0.f;
        }
#pragma unroll
        for (int nt = 0; nt < 8; nt++) {
            int cN = nt * 16 + lr;
            float bv = bias[cN];
#pragma unroll
            for (int i = 0; i < 4; i++) {
                int m = bm + wv * 16 + q * 4 + i;
                if (m < N_NODES)
                    Ob[(size_t)m * HID_DIM + cN] = bf16r(dv_[i] * fmaxf(acc[nt][i] + bv, 0.f));
            }
        }
    } else {
        // fused mean-pool: write relu'd h-tile into (dead) LDS, run-reduce per column
        __syncthreads();                       // all MFMA LDS reads complete before overwrite
        float* hl = (float*)smem;              // [64][132] fp32 tile (33.8 KB < 52.2 KB)
#pragma unroll
        for (int nt = 0; nt < 8; nt++) {
            int cN = nt * 16 + lr;
            float bv = bias[cN];
#pragma unroll
            for (int i = 0; i < 4; i++) {
                int mr = wv * 16 + q * 4 + i;
                if (bm + mr < N_NODES)
                    hl[mr * 132 + cN] = fmaxf(acc[nt][i] + bv, 0.f);
            }
        }
        __syncthreads();
        if (tid < 128) {
            int f = tid;
            float run = 0.f;
            int cg = sbat[0];
            for (int m = 0; m < 64; m++) {
                int g = sbat[m];
                if (g != cg) {
                    if (cg >= 0) atomicAdd(&psum[cg * HID_DIM + f], run);
                    run = 0.f;
                    cg = g;
                }
                if (g >= 0) run += hl[m * 132 + f];
            }
            if (cg >= 0) atomicAdd(&psum[cg * HID_DIM + f], run);
        }
    }
}

// ---------------- tiny FC head: out[g] = (psum[g]/cnt[g]) @ fcw^T + fcb ----------------

__global__ __launch_bounds__(128) void k_fc(const float* __restrict__ psum,
                                            const int* __restrict__ gstart,
                                            const float* __restrict__ fcw,
                                            const float* __restrict__ fcb,
                                            float* __restrict__ out) {
    const int g = blockIdx.x;
    const int t = threadIdx.x;
    __shared__ float pool[HID_DIM];
    float c = fmaxf((float)(gstart[g + 1] - gstart[g]), 1.f);
    pool[t] = psum[g * HID_DIM + t] / c;
    __syncthreads();
    if (t < OUT_DIM) {
        float a = fcb[t];
#pragma unroll 8
        for (int k = 0; k < HID_DIM; k++)
            a = fmaf(pool[k], fcw[t * HID_DIM + k], a);
        out[g * OUT_DIM + t] = a;
    }
}

// ---------------- launch ----------------

extern "C" void kernel_launch(void* const* d_in, const int* in_sizes, int n_in,
                              void* d_out, int out_size, void* d_ws, size_t ws_size,
                              hipStream_t stream) {
    const float* x   = (const float*)d_in[0];
    const int*  eidx = (const int*)d_in[1];
    const int* batch = (const int*)d_in[2];
    const float* w1  = (const float*)d_in[3];
    const float* b1  = (const float*)d_in[4];
    const float* w2  = (const float*)d_in[5];
    const float* b2  = (const float*)d_in[6];
    const float* fcw = (const float*)d_in[7];
    const float* fcb = (const float*)d_in[8];
    float* out = (float*)d_out;
    const int* src = eidx;             // edge_index[0]
    const int* dst = eidx + N_EDGES;   // edge_index[1]

    char* w = (char*)d_ws;
    unsigned* xs   = (unsigned*)(w);                  //  6,400,000 B  x * dinv (bf16)
    unsigned* aggb = (unsigned*)(w + 6400000);        //  6,400,000 B  layer-1 aggregate (bf16)
    unsigned short* h1s = (unsigned short*)(w + 12800000);  // 12,800,000 B  dinv*relu(h1) (bf16)
    unsigned* agg2 = (unsigned*)(w + 25600000);       // 12,800,000 B  layer-2 aggregate (bf16)
    unsigned* ebuf = (unsigned*)(w + 38400000);       //  3,200,000 B  CSR build scratch
    int*   row_ptr = (int*)  (w + 51200000);          //    200,064 B
    float* dinv    = (float*)(w + 51400064);          //    200,000 B
    unsigned short* col = (unsigned short*)(w + 51600064);  // 1,600,000 B (u16)
    int*   hpart   = (int*)  (w + 53200064);          //    153,664 B (196*196)
    int*   gbase   = (int*)  (w + 53353728);          //        788 B (197 ints)
    int*   gstart  = (int*)  (w + 53354516);          //        260 B
    unsigned* w1b  = (unsigned*)(w + 53355584);       //     16,384 B
    unsigned* w2b  = (unsigned*)(w + 53371968);       //     32,768 B
    float* psum    = (float*)(w + 53404736);          //     32,768 B (64*128 fp32 pooled sums)

    dim3 b256(256);

    // CSR build: hist (+bounds/wpack/psum0) -> self-scan scatter -> fine sort (+xscale)
    k_hist  <<<dim3(NBUCK), b256, 0, stream>>>(dst, batch, w1, w2, hpart, gstart, w1b, w2b, psum);
    k_fill1b<<<dim3(NBUCK), b256, 0, stream>>>(src, dst, hpart, gbase, ebuf);
    k_fill2 <<<dim3(NBUCK), b256, 0, stream>>>(ebuf, gbase, x, row_ptr, dinv, col, xs);

    // layer 1 (aggregate-then-transform, all-bf16 payloads); epilogue pre-scales by dinv
    k_gather64<<<dim3((N_NODES + 31) / 32), b256, 0, stream>>>(xs, row_ptr, col, dinv, aggb);
    k_gemm_mfma<IN_DIM, 1><<<dim3((N_NODES + 63) / 64), b256, 0, stream>>>(
        aggb, w1b, b1, dinv, nullptr, nullptr, h1s);

    // layer 2 (aggregate-then-transform; GEMM epilogue fuses relu + mean-pool)
    k_gather128b<<<dim3(N_NODES / 16), b256, 0, stream>>>(
        (const unsigned*)h1s, row_ptr, col, dinv, agg2);
    k_gemm_mfma<HID_DIM, 2><<<dim3((N_NODES + 63) / 64), b256, 0, stream>>>(
        (const unsigned*)agg2, w2b, b2, nullptr, batch, psum, nullptr);

    // tiny FC head
    k_fc<<<dim3(N_GRAPHS), dim3(128), 0, stream>>>(psum, gstart, fcw, fcb, out);
}